// Round 7
// baseline (105.268 us; speedup 1.0000x reference)
//
#include <hip/hip_runtime.h>
#include <math.h>

#define M_ 48
#define L_ 48
#define N_ 256
#define THREADS 512
#define NWAVE 8
#define PPT 3                  // pairs per thread: one row-chunk of 3 consecutive k

// R16: 4-SITE SPECULATION — rounds 24 -> 12 (2 rounds of 4 sites per 8-site
// segment; ckpt/T/R geometry untouched). Evidence: R14/R15 proved occupancy
// is dead (2 waves/SIMD neutral, spilled or not) => stalls are lockstep at
// the per-round barrier+reduce+decide sequence (~0.3-0.5us x 24 rounds from
// R13's 52% stall budget). 15 hypothesis sums/round (1+2+4+8) pipeline
// through wave_sum63 (latency amortizes, only issue grows ~+350cyc/round);
// 12 round-overheads vanish. Post-reduction selects use nested ternaries on
// named scalars (no runtime-indexed arrays -> no scratch).
// Calibration (R12/R13, 3-point): dur_us = ~60us harness floor + kernel;
// kernel currently ~24us. Predict ~20-21us -> dur ~80-82.5.
// Post-mortems: R11 f32-LDS-table NEUTRAL; R14 full-stash@512thr spill
// (VGPR 112) neutral; R15 despilled lazy-reload neutral => H2 serial-bound.
// Dead ends: R8 2x3 tiles, R9 spread prefetch, R10 stash capture, occupancy.
struct ChunkTab { short cm[THREADS]; short ck0[THREADS]; };
constexpr ChunkTab make_tab() {
    ChunkTab t{};
    int bsz[16] = {};
    for (int m = 0; m < 48; ++m)
        for (int j = 0; PPT * j < 48 - m; ++j) bsz[(m + PPT * j) & 15]++;
    int slot = 0;
    for (int r = 0; r < 64; ++r)
        for (int b = 0; b < 16; ++b)
            if (bsz[b] > r) {
                int cnt = 0;
                for (int m = 0; m < 48; ++m)
                    for (int j = 0; PPT * j < 48 - m; ++j)
                        if (((m + PPT * j) & 15) == b) {
                            if (cnt == r) { t.cm[slot] = (short)m; t.ck0[slot] = (short)(m + PPT * j); }
                            ++cnt;
                        }
                ++slot;
            }
    for (; slot < THREADS; ++slot) { t.cm[slot] = 0; t.ck0[slot] = 127; }  // dummy: weights 0
    return t;
}
__device__ constexpr ChunkTab g_tab = make_tab();

// f64 DPP wave-sum; lane 63 ends with the 64-lane total.
template<int CTRL, int RMASK>
__device__ __forceinline__ double dpp_add(double v) {
    int lo = __builtin_amdgcn_update_dpp(0, __double2loint(v), CTRL, RMASK, 0xf, true);
    int hi = __builtin_amdgcn_update_dpp(0, __double2hiint(v), CTRL, RMASK, 0xf, true);
    return v + __hiloint2double(hi, lo);
}
__device__ __forceinline__ double wave_sum63(double v) {
    v = dpp_add<0x111, 0xf>(v);   // row_shr:1
    v = dpp_add<0x112, 0xf>(v);   // row_shr:2
    v = dpp_add<0x114, 0xf>(v);   // row_shr:4
    v = dpp_add<0x118, 0xf>(v);   // row_shr:8
    v = dpp_add<0x142, 0xa>(v);   // row_bcast15
    v = dpp_add<0x143, 0xc>(v);   // row_bcast31 -> lane63 = total
    return v;
}

__launch_bounds__(THREADS, 2)
__global__ void mps_sample_kernel(const float* __restrict__ inp,
                                  const float* __restrict__ theta,
                                  const float* __restrict__ coef,
                                  const float* __restrict__ rand_u,
                                  float* __restrict__ out)
{
    const int n   = blockIdx.x;
    const int tid = threadIdx.x;

    __shared__ float  s_pxy[L_][M_][2];        // (px,py) f32 interleaved, b64-readable
    __shared__ double s_part[2][16][NWAVE];    // [parity][hypothesis][wave]
    __shared__ float  s_u[L_];

    const double PI_2 = 1.5707963267948966;

    // ---- trig init: pxy[l][m] = coef[m] * (cos, sin)(theta + inp*(m+1)*pi/2) ----
    #pragma unroll
    for (int i = 0; i < 5; ++i) {
        int j = tid + THREADS * i;
        if (j < L_ * M_) {
            int l = j / M_, m = j - l * M_;
            double a  = (double)inp[n * L_ + l] * ((double)(m + 1) * PI_2);
            double th = (double)theta[l * M_ + m];
            double sv, cv; sincos(th + a, &sv, &cv);
            double cf = (double)coef[m];
            s_pxy[l][m][0] = (float)(cf * cv);
            s_pxy[l][m][1] = (float)(cf * sv);
        }
    }
    if (tid < L_) s_u[tid] = rand_u[tid * N_ + n];

    // ---- row-chunk pair assignment: 3 pairs (cm, k0..k0+2) per thread ----
    const int cm = g_tab.cm[tid];
    const int k0 = g_tab.ck0[tid];
    int pk[PPT]; double wgt[PPT];
    #pragma unroll
    for (int i = 0; i < PPT; ++i) {
        int k = k0 + i;
        wgt[i] = (k > 47) ? 0.0 : ((k == cm) ? 1.0 : 2.0);
        pk[i]  = (k > 47) ? 47 : k;
    }
    __syncthreads();

    // ---- register checkpoints: ckpt[s] = w * prod_{l'>=8(s+1)} T_l' ----
    double ckpt[5][PPT];
    {
        double C[PPT];
        #pragma unroll
        for (int i = 0; i < PPT; ++i) C[i] = wgt[i];
        #pragma unroll
        for (int s = 4; s >= 0; --s) {
            #pragma unroll
            for (int lp = 7; lp >= 0; --lp) {
                int l = 8 * (s + 1) + lp;              // 47 .. 8
                float2 vm = *(const float2*)&s_pxy[l][cm][0];   // shared per thread
                #pragma unroll
                for (int i = 0; i < PPT; ++i) {
                    float2 vk = *(const float2*)&s_pxy[l][pk[i]][0];
                    C[i] *= (double)fmaf(vm.x, vk.x, vm.y * vk.y);
                }
            }
            #pragma unroll
            for (int i = 0; i < PPT; ++i) ckpt[s][i] = C[i];
        }
    }

    double G[PPT];
    #pragma unroll
    for (int i = 0; i < PPT; ++i) G[i] = 1.0;

    double denom = 0.0, initd = 1.0;
    float  myBit = 0.0f;

    #pragma unroll
    for (int seg = 0; seg < 6; ++seg) {
        // ---- segment T-stash: T[j][i] = X+Y only (1 vm + 3 vk b64 loads/site) ----
        double T[8][PPT];
        #pragma unroll
        for (int j = 0; j < 8; ++j) {
            int l2 = 8 * seg + j;
            float2 vm = *(const float2*)&s_pxy[l2][cm][0];
            #pragma unroll
            for (int i = 0; i < PPT; ++i) {
                float2 vk = *(const float2*)&s_pxy[l2][pk[i]][0];
                T[j][i] = (double)(vm.x * vk.x) + (double)(vm.y * vk.y);
            }
        }
        // ---- register expansion: R[j] = w * S_{8seg+j+1}; T dies after this ----
        double R[8][PPT];
        #pragma unroll
        for (int i = 0; i < PPT; ++i)
            R[7][i] = (seg == 5) ? wgt[i] : ckpt[seg == 5 ? 0 : seg][i];
        #pragma unroll
        for (int j = 6; j >= 0; --j)
            #pragma unroll
            for (int i = 0; i < PPT; ++i)
                R[j][i] = R[j + 1][i] * T[j + 1][i];

        // ---- 2 rounds x 4 speculative sites, DPP-reduced ----
        #pragma unroll
        for (int halfq = 0; halfq < 2; ++halfq) {
            const int ls    = 4 * halfq;
            const int l     = 8 * seg + ls;
            const int par   = halfq;
            const bool first = (seg == 0 && halfq == 0);
            // lazy X/Y reload for the four sites of this round (post-barrier
            // region; overlaps the previous round's decision chain).
            float2 vm0 = *(const float2*)&s_pxy[l][cm][0];
            float2 vm1 = *(const float2*)&s_pxy[l + 1][cm][0];
            float2 vm2 = *(const float2*)&s_pxy[l + 2][cm][0];
            float2 vm3 = *(const float2*)&s_pxy[l + 3][cm][0];
            double X0[PPT], Y0[PPT], X1[PPT], Y1[PPT];
            double X2[PPT], Y2[PPT], X3[PPT], Y3[PPT];
            #pragma unroll
            for (int i = 0; i < PPT; ++i) {
                float2 vk0 = *(const float2*)&s_pxy[l][pk[i]][0];
                float2 vk1 = *(const float2*)&s_pxy[l + 1][pk[i]][0];
                float2 vk2 = *(const float2*)&s_pxy[l + 2][pk[i]][0];
                float2 vk3 = *(const float2*)&s_pxy[l + 3][pk[i]][0];
                X0[i] = (double)(vm0.x * vk0.x);  Y0[i] = (double)(vm0.y * vk0.y);
                X1[i] = (double)(vm1.x * vk1.x);  Y1[i] = (double)(vm1.y * vk1.y);
                X2[i] = (double)(vm2.x * vk2.x);  Y2[i] = (double)(vm2.y * vk2.y);
                X3[i] = (double)(vm3.x * vk3.x);  Y3[i] = (double)(vm3.y * vk3.y);
            }
            // 15 hypothesis sums: site l (1), l+1 (2), l+2 (4), l+3 (8)
            double n1 = 0.0, nT = 0.0;
            double h0 = 0.0, h1 = 0.0;
            double hh00 = 0.0, hh01 = 0.0, hh10 = 0.0, hh11 = 0.0;
            double k000 = 0.0, k001 = 0.0, k010 = 0.0, k011 = 0.0;
            double k100 = 0.0, k101 = 0.0, k110 = 0.0, k111 = 0.0;
            #pragma unroll
            for (int i = 0; i < PPT; ++i) {
                double t0 = G[i] * R[ls][i];
                double t1 = G[i] * R[ls + 1][i];
                double t2 = G[i] * R[ls + 2][i];
                double t3 = G[i] * R[ls + 3][i];
                n1 = fma(t0, Y0[i], n1);
                if (first) nT = fma(t0, X0[i], nT);           // denom seed
                double a0 = t1 * X0[i], a1 = t1 * Y0[i];
                h0 = fma(a0, Y1[i], h0);
                h1 = fma(a1, Y1[i], h1);
                double b0 = t2 * X0[i], b1 = t2 * Y0[i];
                double b00 = b0 * X1[i], b01 = b0 * Y1[i];
                double b10 = b1 * X1[i], b11 = b1 * Y1[i];
                hh00 = fma(b00, Y2[i], hh00);
                hh01 = fma(b01, Y2[i], hh01);
                hh10 = fma(b10, Y2[i], hh10);
                hh11 = fma(b11, Y2[i], hh11);
                double e0 = t3 * X0[i], e1 = t3 * Y0[i];
                double e00 = e0 * X1[i], e01 = e0 * Y1[i];
                double e10 = e1 * X1[i], e11 = e1 * Y1[i];
                k000 = fma(e00 * X2[i], Y3[i], k000);
                k001 = fma(e00 * Y2[i], Y3[i], k001);
                k010 = fma(e01 * X2[i], Y3[i], k010);
                k011 = fma(e01 * Y2[i], Y3[i], k011);
                k100 = fma(e10 * X2[i], Y3[i], k100);
                k101 = fma(e10 * Y2[i], Y3[i], k101);
                k110 = fma(e11 * X2[i], Y3[i], k110);
                k111 = fma(e11 * Y2[i], Y3[i], k111);
            }
            n1   = wave_sum63(n1);
            h0   = wave_sum63(h0);   h1   = wave_sum63(h1);
            hh00 = wave_sum63(hh00); hh01 = wave_sum63(hh01);
            hh10 = wave_sum63(hh10); hh11 = wave_sum63(hh11);
            k000 = wave_sum63(k000); k001 = wave_sum63(k001);
            k010 = wave_sum63(k010); k011 = wave_sum63(k011);
            k100 = wave_sum63(k100); k101 = wave_sum63(k101);
            k110 = wave_sum63(k110); k111 = wave_sum63(k111);
            if (first) nT = wave_sum63(nT);
            if ((tid & 63) == 63) {                 // lane 63 holds wave totals
                const int wv = tid >> 6;
                s_part[par][0][wv]  = n1;
                s_part[par][1][wv]  = h0;   s_part[par][2][wv]  = h1;
                s_part[par][3][wv]  = hh00; s_part[par][4][wv]  = hh01;
                s_part[par][5][wv]  = hh10; s_part[par][6][wv]  = hh11;
                s_part[par][7][wv]  = k000; s_part[par][8][wv]  = k001;
                s_part[par][9][wv]  = k010; s_part[par][10][wv] = k011;
                s_part[par][11][wv] = k100; s_part[par][12][wv] = k101;
                s_part[par][13][wv] = k110; s_part[par][14][wv] = k111;
                if (first) s_part[par][15][wv] = nT;
            }
            __syncthreads();
            // cross-wave readback (broadcast reads, all threads same address)
            auto rd8 = [&](int v) -> double {
                double2 a = *(const double2*)&s_part[par][v][0];
                double2 b = *(const double2*)&s_part[par][v][2];
                double2 c = *(const double2*)&s_part[par][v][4];
                double2 d = *(const double2*)&s_part[par][v][6];
                return ((a.x + a.y) + (b.x + b.y)) + ((c.x + c.y) + (d.x + d.y));
            };
            double S_n1   = rd8(0);
            double S_h0   = rd8(1),  S_h1   = rd8(2);
            double S_hh00 = rd8(3),  S_hh01 = rd8(4);
            double S_hh10 = rd8(5),  S_hh11 = rd8(6);
            double S_k000 = rd8(7),  S_k001 = rd8(8);
            double S_k010 = rd8(9),  S_k011 = rd8(10);
            double S_k100 = rd8(11), S_k101 = rd8(12);
            double S_k110 = rd8(13), S_k111 = rd8(14);
            if (first) {
                double snT = rd8(15);
                denom = fabs(snT + S_n1);
                initd = denom;
            }
            // four bit decisions, division-free (denom = <psi|psi> > 0)
            double v1 = fabs(S_n1);
            int bitA  = ((double)s_u[l] * denom < v1) ? 1 : 0;
            denom     = bitA ? v1 : fabs(denom - S_n1);
            double nB = bitA ? S_h1 : S_h0;
            double v2 = fabs(nB);
            int bitB  = ((double)s_u[l + 1] * denom < v2) ? 1 : 0;
            denom     = bitB ? v2 : fabs(denom - nB);
            double nC = bitA ? (bitB ? S_hh11 : S_hh10)
                             : (bitB ? S_hh01 : S_hh00);
            double v3 = fabs(nC);
            int bitC  = ((double)s_u[l + 2] * denom < v3) ? 1 : 0;
            denom     = bitC ? v3 : fabs(denom - nC);
            double nD0 = bitB ? (bitC ? S_k011 : S_k010)
                              : (bitC ? S_k001 : S_k000);
            double nD1 = bitB ? (bitC ? S_k111 : S_k110)
                              : (bitC ? S_k101 : S_k100);
            double nD = bitA ? nD1 : nD0;
            double v4 = fabs(nD);
            int bitD  = ((double)s_u[l + 3] * denom < v4) ? 1 : 0;
            denom     = bitD ? v4 : fabs(denom - nD);
            // fused four-step prefix update from the reloaded values
            #pragma unroll
            for (int i = 0; i < PPT; ++i) {
                double f0 = bitA ? Y0[i] : X0[i];
                double f1 = bitB ? Y1[i] : X1[i];
                double f2 = bitC ? Y2[i] : X2[i];
                double f3 = bitD ? Y3[i] : X3[i];
                G[i] *= (f0 * f1) * (f2 * f3);
            }
            if (tid == l)     myBit = (float)bitA;
            if (tid == l + 1) myBit = (float)bitB;
            if (tid == l + 2) myBit = (float)bitC;
            if (tid == l + 3) myBit = (float)bitD;
        }
    }

    if (tid < L_)  out[n * L_ + tid] = myBit;                 // bits, one burst
    if (tid == 0)  out[N_ * L_ + n] = (float)(denom / initd); // P_m carried free
}

extern "C" void kernel_launch(void* const* d_in, const int* in_sizes, int n_in,
                              void* d_out, int out_size, void* d_ws, size_t ws_size,
                              hipStream_t stream) {
    const float* inp    = (const float*)d_in[0];   // (N,L)
    const float* theta  = (const float*)d_in[1];   // (L,M)
    const float* coef   = (const float*)d_in[2];   // (M,)
    const float* rand_u = (const float*)d_in[3];   // (L,N)
    float* out = (float*)d_out;                    // N*L bits then N probs
    mps_sample_kernel<<<N_, THREADS, 0, stream>>>(inp, theta, coef, rand_u, out);
}

// Round 8
// 83.255 us; speedup vs baseline: 1.2644x; 1.2644x over previous
//
#include <hip/hip_runtime.h>
#include <math.h>

#define M_ 48
#define L_ 48
#define N_ 256
#define THREADS 256
#define NWAVE 4
#define PPT 5                  // pairs per thread: one row-chunk of 5 consecutive k

// R17: CONSOLIDATION — revert to R7 (measured best, 82.5-82.8 us) + one
// issue-only micro-opt (shared-factor w = t1*Y1 in the hypothesis loop:
// -120 f64 mul/thread; ~1 ulp reassociation vs >=1e-5 decision margins).
//
// Session ledger (R11-R16), all measured:
//   kernel ~24 us over a ~59-60 us harness floor (fills+launch); calibrated
//   via 5-launch slope (R12) and in-kernel REP=4 probe (R13: VALUBusy 47.5%,
//   VGPR 204 no-spill, bank-conflict ~6%, 1 wave/SIMD).
//   CLOSED: f32 LDS table (R11 neutral); 2 waves/SIMD spilled (R14, VGPR
//   112) and de-spilled via lazy reload (R15) both neutral -> stalls are
//   lockstep at the per-round reduce, TLP can't fill them; 4-site
//   speculation (R16: 105 us — reduction issue scales with hypothesis
//   count, spill to VGPR 96; round overhead measured <~0.15 us so
//   speculation depth >2 is net-negative). Prior: R8 2x3 tiles, R9 spread
//   prefetch, R10 stash capture (spill -> FETCH x8).
//   Trust bench dur_us (+slope), not profiled kernel rows at 512 thr (R14
//   artifact); fills ~39.5 us x2 at 85% HBM peak are harness-fixed.
struct ChunkTab { short cm[256]; short ck0[256]; };
constexpr ChunkTab make_tab() {
    ChunkTab t{};
    int bsz[8] = {};
    for (int m = 0; m < 48; ++m)
        for (int j = 0; 5 * j < 48 - m; ++j) bsz[(m + 5 * j) & 7]++;
    int slot = 0;
    for (int r = 0; r < 48; ++r)
        for (int b = 0; b < 8; ++b)
            if (bsz[b] > r) {
                int cnt = 0;
                for (int m = 0; m < 48; ++m)
                    for (int j = 0; 5 * j < 48 - m; ++j)
                        if (((m + 5 * j) & 7) == b) {
                            if (cnt == r) { t.cm[slot] = (short)m; t.ck0[slot] = (short)(m + 5 * j); }
                            ++cnt;
                        }
                ++slot;
            }
    for (; slot < 256; ++slot) { t.cm[slot] = 0; t.ck0[slot] = 127; }  // dummy: weights 0
    return t;
}
__device__ constexpr ChunkTab g_tab = make_tab();

// f64 DPP wave-sum; lane 63 ends with the 64-lane total (VALU-latency stages,
// not ds_bpermute: R7's key win).
template<int CTRL, int RMASK>
__device__ __forceinline__ double dpp_add(double v) {
    int lo = __builtin_amdgcn_update_dpp(0, __double2loint(v), CTRL, RMASK, 0xf, true);
    int hi = __builtin_amdgcn_update_dpp(0, __double2hiint(v), CTRL, RMASK, 0xf, true);
    return v + __hiloint2double(hi, lo);
}
__device__ __forceinline__ double wave_sum63(double v) {
    v = dpp_add<0x111, 0xf>(v);   // row_shr:1
    v = dpp_add<0x112, 0xf>(v);   // row_shr:2
    v = dpp_add<0x114, 0xf>(v);   // row_shr:4
    v = dpp_add<0x118, 0xf>(v);   // row_shr:8
    v = dpp_add<0x142, 0xa>(v);   // row_bcast15
    v = dpp_add<0x143, 0xc>(v);   // row_bcast31 -> lane63 = total
    return v;
}

__launch_bounds__(THREADS, 1)
__global__ void mps_sample_kernel(const float* __restrict__ inp,
                                  const float* __restrict__ theta,
                                  const float* __restrict__ coef,
                                  const float* __restrict__ rand_u,
                                  float* __restrict__ out)
{
    const int n   = blockIdx.x;
    const int tid = threadIdx.x;

    __shared__ double s_pxy[L_][M_][2];        // (px,py) interleaved, b128-readable
    __shared__ double s_part[2][4][NWAVE];     // [parity][value][wave]
    __shared__ float  s_u[L_];

    const double PI_2 = 1.5707963267948966;

    // ---- trig init: pxy[l][m] = coef[m] * (cos, sin)(theta + inp*(m+1)*pi/2) ----
    #pragma unroll
    for (int i = 0; i < 9; ++i) {
        int j = tid + THREADS * i;
        int l = j / M_, m = j - l * M_;
        double a  = (double)inp[n * L_ + l] * ((double)(m + 1) * PI_2);
        double th = (double)theta[l * M_ + m];
        double sv, cv; sincos(th + a, &sv, &cv);
        double cf = (double)coef[m];
        s_pxy[l][m][0] = cf * cv;
        s_pxy[l][m][1] = cf * sv;
    }
    if (tid < L_) s_u[tid] = rand_u[tid * N_ + n];

    // ---- row-chunk pair assignment: 5 pairs (cm, k0..k0+4) per thread ----
    const int cm = g_tab.cm[tid];
    const int k0 = g_tab.ck0[tid];
    int pk[PPT]; double wgt[PPT];
    #pragma unroll
    for (int i = 0; i < PPT; ++i) {
        int k = k0 + i;
        wgt[i] = (k > 47) ? 0.0 : ((k == cm) ? 1.0 : 2.0);
        pk[i]  = (k > 47) ? 47 : k;
    }
    __syncthreads();

    // ---- register checkpoints: ckpt[s] = w * prod_{l'>=8(s+1)} T_l' ----
    double ckpt[5][PPT];
    {
        double C[PPT];
        #pragma unroll
        for (int i = 0; i < PPT; ++i) C[i] = wgt[i];
        #pragma unroll
        for (int s = 4; s >= 0; --s) {
            #pragma unroll
            for (int lp = 7; lp >= 0; --lp) {
                int l = 8 * (s + 1) + lp;              // 47 .. 8
                double2 vm = *(const double2*)&s_pxy[l][cm][0];   // shared per thread
                #pragma unroll
                for (int i = 0; i < PPT; ++i) {
                    double2 vk = *(const double2*)&s_pxy[l][pk[i]][0];
                    C[i] *= vm.x * vk.x + vm.y * vk.y;
                }
            }
            #pragma unroll
            for (int i = 0; i < PPT; ++i) ckpt[s][i] = C[i];
        }
    }

    double G[PPT];
    #pragma unroll
    for (int i = 0; i < PPT; ++i) G[i] = 1.0;

    double denom = 0.0, initd = 1.0;
    float  myBit = 0.0f;

    #pragma unroll
    for (int seg = 0; seg < 6; ++seg) {
        // ---- segment stash: X[j][i], Y[j][i] (1 vm + 5 vk loads per site) ----
        double X[8][PPT], Y[8][PPT];
        #pragma unroll
        for (int j = 0; j < 8; ++j) {
            int l2 = 8 * seg + j;
            double2 vm = *(const double2*)&s_pxy[l2][cm][0];
            #pragma unroll
            for (int i = 0; i < PPT; ++i) {
                double2 vk = *(const double2*)&s_pxy[l2][pk[i]][0];
                X[j][i] = vm.x * vk.x;
                Y[j][i] = vm.y * vk.y;
            }
        }
        // ---- register expansion from stash: R[j] = w * S_{8seg+j+1} ----
        double R[8][PPT];
        #pragma unroll
        for (int i = 0; i < PPT; ++i)
            R[7][i] = (seg == 5) ? wgt[i] : ckpt[seg == 5 ? 0 : seg][i];
        #pragma unroll
        for (int j = 6; j >= 0; --j)
            #pragma unroll
            for (int i = 0; i < PPT; ++i)
                R[j][i] = R[j + 1][i] * (X[j + 1][i] + Y[j + 1][i]);

        // ---- 4 iterations x 2 speculative steps, DPP-reduced ----
        #pragma unroll
        for (int half = 0; half < 4; ++half) {
            const int ls  = 2 * half;
            const int l   = 8 * seg + ls;
            const int par = half & 1;
            double n1L = 0.0, h0 = 0.0, h1 = 0.0, nT = 0.0;
            #pragma unroll
            for (int i = 0; i < PPT; ++i) {
                double t0 = G[i] * R[ls][i];
                double t1 = G[i] * R[ls + 1][i];
                n1L = fma(t0, Y[ls][i], n1L);
                if (seg == 0 && half == 0) nT = fma(t0, X[0][i], nT); // denom seed
                double w = t1 * Y[ls + 1][i];        // shared factor (R17)
                h0 = fma(w, X[ls][i], h0);           // hypothesis bit_l = 0
                h1 = fma(w, Y[ls][i], h1);           // hypothesis bit_l = 1
            }
            n1L = wave_sum63(n1L);
            h0  = wave_sum63(h0);
            h1  = wave_sum63(h1);
            if (seg == 0 && half == 0) nT = wave_sum63(nT);
            if ((tid & 63) == 63) {                 // lane 63 holds wave totals
                const int wv = tid >> 6;
                s_part[par][0][wv] = n1L; s_part[par][1][wv] = h0;
                s_part[par][2][wv] = h1;
                if (seg == 0 && half == 0) s_part[par][3][wv] = nT;
            }
            __syncthreads();
            double2 a0 = *(const double2*)&s_part[par][0][0];
            double2 b0 = *(const double2*)&s_part[par][0][2];
            double2 a1 = *(const double2*)&s_part[par][1][0];
            double2 b1 = *(const double2*)&s_part[par][1][2];
            double2 a2 = *(const double2*)&s_part[par][2][0];
            double2 b2 = *(const double2*)&s_part[par][2][2];
            double sn1 = (a0.x + a0.y) + (b0.x + b0.y);
            double sh0 = (a1.x + a1.y) + (b1.x + b1.y);
            double sh1 = (a2.x + a2.y) + (b2.x + b2.y);
            if (seg == 0 && half == 0) {
                double2 a3 = *(const double2*)&s_part[par][3][0];
                double2 b3 = *(const double2*)&s_part[par][3][2];
                double snT = (a3.x + a3.y) + (b3.x + b3.y);
                denom = fabs(snT + sn1);
                initd = denom;
            }
            // two bit decisions, division-free (denom = <psi|psi> > 0)
            double v1 = fabs(sn1);
            int bitA   = ((double)s_u[l] * denom < v1) ? 1 : 0;
            denom      = bitA ? v1 : fabs(denom - sn1);
            double n1b = bitA ? sh1 : sh0;
            double v2  = fabs(n1b);
            int bitB   = ((double)s_u[l + 1] * denom < v2) ? 1 : 0;
            denom      = bitB ? v2 : fabs(denom - n1b);
            // fused two-step prefix update from stash
            #pragma unroll
            for (int i = 0; i < PPT; ++i) {
                double c0 = bitA ? Y[ls][i]     : X[ls][i];
                double c1 = bitB ? Y[ls + 1][i] : X[ls + 1][i];
                G[i] *= c0 * c1;
            }
            if (tid == l)     myBit = (float)bitA;
            if (tid == l + 1) myBit = (float)bitB;
        }
    }

    if (tid < L_)  out[n * L_ + tid] = myBit;                 // bits, one burst
    if (tid == 0)  out[N_ * L_ + n] = (float)(denom / initd); // P_m carried free
}

extern "C" void kernel_launch(void* const* d_in, const int* in_sizes, int n_in,
                              void* d_out, int out_size, void* d_ws, size_t ws_size,
                              hipStream_t stream) {
    const float* inp    = (const float*)d_in[0];   // (N,L)
    const float* theta  = (const float*)d_in[1];   // (L,M)
    const float* coef   = (const float*)d_in[2];   // (M,)
    const float* rand_u = (const float*)d_in[3];   // (L,N)
    float* out = (float*)d_out;                    // N*L bits then N probs
    mps_sample_kernel<<<N_, THREADS, 0, stream>>>(inp, theta, coef, rand_u, out);
}